// Round 2
// baseline (536.819 us; speedup 1.0000x reference)
//
#include <hip/hip_runtime.h>

// gcd(a,b)*W_gcd -> out[0..N), (a%p)*W_mod -> out[N..2N)
// a,b in [0,1e6), p in [1,1e6): all fit in 20 bits, nonnegative.

__device__ __forceinline__ unsigned gcd_u32(unsigned a, unsigned b) {
    if (a == 0u) return b;
    if (b == 0u) return a;
    unsigned s = __builtin_ctz(a | b);
    a >>= __builtin_ctz(a);
    do {
        b >>= __builtin_ctz(b);
        if (a > b) { unsigned t = a; a = b; b = t; }
        b -= a;
    } while (b != 0u);
    return a << s;
}

__global__ __launch_bounds__(256) void ntb_kernel(
    const int4* __restrict__ a4, const int4* __restrict__ b4,
    const int4* __restrict__ p4,
    const float* __restrict__ Wg, const float* __restrict__ Wm,
    float4* __restrict__ gcd_out, float4* __restrict__ mod_out, int n4)
{
    const float wg = Wg[0];
    const float wm = Wm[0];
    const int stride = gridDim.x * blockDim.x;
    for (int i = blockIdx.x * blockDim.x + threadIdx.x; i < n4; i += stride) {
        const int4 av = a4[i];
        const int4 bv = b4[i];
        const int4 pv = p4[i];

        float4 g, m;
        g.x = (float)gcd_u32((unsigned)av.x, (unsigned)bv.x) * wg;
        g.y = (float)gcd_u32((unsigned)av.y, (unsigned)bv.y) * wg;
        g.z = (float)gcd_u32((unsigned)av.z, (unsigned)bv.z) * wg;
        g.w = (float)gcd_u32((unsigned)av.w, (unsigned)bv.w) * wg;

        m.x = (float)((unsigned)av.x % (unsigned)pv.x) * wm;
        m.y = (float)((unsigned)av.y % (unsigned)pv.y) * wm;
        m.z = (float)((unsigned)av.z % (unsigned)pv.z) * wm;
        m.w = (float)((unsigned)av.w % (unsigned)pv.w) * wm;

        gcd_out[i] = g;
        mod_out[i] = m;
    }
}

extern "C" void kernel_launch(void* const* d_in, const int* in_sizes, int n_in,
                              void* d_out, int out_size, void* d_ws, size_t ws_size,
                              hipStream_t stream) {
    const int n = in_sizes[0];           // 2^25
    const int n4 = n >> 2;               // int4 groups (N divisible by 4)

    const int4* a4 = (const int4*)d_in[0];
    const int4* b4 = (const int4*)d_in[1];
    const int4* p4 = (const int4*)d_in[2];
    const float* Wg = (const float*)d_in[3];
    const float* Wm = (const float*)d_in[4];

    float* out = (float*)d_out;
    float4* gcd_out = (float4*)out;        // first N floats
    float4* mod_out = (float4*)(out + n);  // second N floats

    const int block = 256;
    const int grid = 2048;  // 8192 waves: full residency, grid-stride the rest

    ntb_kernel<<<grid, block, 0, stream>>>(a4, b4, p4, Wg, Wm, gcd_out, mod_out, n4);
}

// Round 3
// 534.899 us; speedup vs baseline: 1.0036x; 1.0036x over previous
//
#include <hip/hip_runtime.h>

// gcd(a,b)*W_gcd -> out[0..N), (a%p)*W_mod -> out[N..2N)
// a,b in [0,1e6), p in [1,1e6): all values fit in 20 bits, nonnegative.
//
// GCD: binary, 4-way interleaved, masking-free fixed point.
//   Invariant: once a pair reaches (0, g_odd) it stays there:
//     b >>= ctz(b|GUARD) leaves 0 or odd alone; a'=min(a,b), b'=|a-b|
//     maps (0,g) -> (0,g). So no per-value predication; loop exits when
//     all four A's are zero. Result = (A|B) << S.
// MOD: exact fp32 (all ints < 2^20 < 2^24): q=trunc(a*rcp(p)),
//   r=fma(-q,p,a) exact, then two range fixups into [0,p).

__global__ __launch_bounds__(256) void ntb_kernel(
    const int4* __restrict__ a4, const int4* __restrict__ b4,
    const int4* __restrict__ p4,
    const float* __restrict__ Wg, const float* __restrict__ Wm,
    float4* __restrict__ gcd_out, float4* __restrict__ mod_out, int n4)
{
    const float wg = Wg[0];
    const float wm = Wm[0];
    const unsigned GUARD = 1u << 21;  // above any live bit; caps ctz(0) shift
    const int stride = gridDim.x * blockDim.x;

    for (int i = blockIdx.x * blockDim.x + threadIdx.x; i < n4; i += stride) {
        const int4 av = a4[i];
        const int4 bv = b4[i];
        const int4 pv = p4[i];

        unsigned A[4] = {(unsigned)av.x, (unsigned)av.y, (unsigned)av.z, (unsigned)av.w};
        unsigned B[4] = {(unsigned)bv.x, (unsigned)bv.y, (unsigned)bv.z, (unsigned)bv.w};
        unsigned S[4];
        #pragma unroll
        for (int v = 0; v < 4; ++v) {
            S[v] = (unsigned)__builtin_ctz(A[v] | B[v] | GUARD);
            A[v] >>= __builtin_ctz(A[v] | GUARD);   // a=0 -> stays 0
            B[v] >>= __builtin_ctz(B[v] | GUARD);   // pre-strip b (a==0 case exact)
        }

        while ((A[0] | A[1] | A[2] | A[3]) != 0u) {
            #pragma unroll
            for (int v = 0; v < 4; ++v) {
                unsigned b  = B[v] >> __builtin_ctz(B[v] | GUARD);
                unsigned nb = __usad(A[v], b, 0u);   // |a - b|, single v_sad_u32
                A[v] = min(A[v], b);
                B[v] = nb;
            }
        }

        float4 g;
        g.x = (float)((A[0] | B[0]) << S[0]) * wg;
        g.y = (float)((A[1] | B[1]) << S[1]) * wg;
        g.z = (float)((A[2] | B[2]) << S[2]) * wg;
        g.w = (float)((A[3] | B[3]) << S[3]) * wg;

        const unsigned au[4] = {(unsigned)av.x, (unsigned)av.y, (unsigned)av.z, (unsigned)av.w};
        const unsigned pu[4] = {(unsigned)pv.x, (unsigned)pv.y, (unsigned)pv.z, (unsigned)pv.w};
        float mm[4];
        #pragma unroll
        for (int v = 0; v < 4; ++v) {
            const float af = (float)au[v];
            const float pf = (float)pu[v];
            const float q  = truncf(af * __builtin_amdgcn_rcpf(pf));
            float r = fmaf(-q, pf, af);              // exact: |r| < 2^21
            r += (r < 0.0f)  ? pf : 0.0f;            // q was floor+1
            r -= (r >= pf)   ? pf : 0.0f;            // q was floor-1
            mm[v] = r * wm;
        }
        float4 m;
        m.x = mm[0]; m.y = mm[1]; m.z = mm[2]; m.w = mm[3];

        gcd_out[i] = g;
        mod_out[i] = m;
    }
}

extern "C" void kernel_launch(void* const* d_in, const int* in_sizes, int n_in,
                              void* d_out, int out_size, void* d_ws, size_t ws_size,
                              hipStream_t stream) {
    const int n  = in_sizes[0];   // 2^25
    const int n4 = n >> 2;

    const int4* a4 = (const int4*)d_in[0];
    const int4* b4 = (const int4*)d_in[1];
    const int4* p4 = (const int4*)d_in[2];
    const float* Wg = (const float*)d_in[3];
    const float* Wm = (const float*)d_in[4];

    float* out = (float*)d_out;
    float4* gcd_out = (float4*)out;        // first N floats
    float4* mod_out = (float4*)(out + n);  // second N floats

    const int block = 256;
    const int grid  = 2048;  // 8 blocks/CU, grid-stride covers 8M int4 groups

    ntb_kernel<<<grid, block, 0, stream>>>(a4, b4, p4, Wg, Wm, gcd_out, mod_out, n4);
}